// Round 3
// baseline (552.175 us; speedup 1.0000x reference)
//
#include <hip/hip_runtime.h>
#include <math.h>

// WaveletLayerND: fused mexican-hat wavelet + grouped 3x3 conv (kernel 1),
// then 1x1 channel mix (kernel 2). B=4, O=I=32, H=W=128, fp32 throughout.
//
// Kernel 1 layout: 256-thread blocks = 4 waves = one o-channel, i split 4-way
// (8 input channels per wave). 16 strips x 32 o x 4 b = 2048 blocks -> ~6
// blocks/CU (VGPR-capped) = ~24 waves/CU. Halo cost stays 1.25x (RSTRIP=8).
// 3 waves write partials to LDS; wave 0 reduces and stores y.

#define RSTRIP 8   // output rows per wave

__global__ __launch_bounds__(256, 6) void wavelet_grouped_conv(
    const float* __restrict__ x,      // (B, I, H, W)
    const float* __restrict__ scale,  // (O*I)
    const float* __restrict__ trans,  // (O*I)
    const float* __restrict__ wconv,  // (O, I, 3, 3)
    float* __restrict__ y,            // (B, O, H, W) workspace
    float mhc)
{
  const int tid   = threadIdx.x;
  const int lane  = tid & 63;
  const int iq    = tid >> 6;          // 0..3: which i-quarter this wave owns
  const int strip = blockIdx.x;        // 0..15
  const int o     = blockIdx.y;        // 0..31
  const int b     = blockIdx.z;        // 0..3
  const int r0    = strip * RSTRIP;
  const int c0    = lane << 1;         // this thread's two columns

  const float NHL2E = -0.72134752044448170f; // -0.5 * log2(e)

  float acc[RSTRIP][2];
#pragma unroll
  for (int r = 0; r < RSTRIP; ++r) { acc[r][0] = 0.f; acc[r][1] = 0.f; }

  const float* xb = x + (size_t)b * 32 * 128 * 128;

#pragma unroll
  for (int ii = 0; ii < 8; ii += 2) {
    const int i0 = iq * 8 + ii;                 // wave-uniform
    const int oi0 = __builtin_amdgcn_readfirstlane(o * 32 + i0);
    const int oi1 = oi0 + 1;
    const float rs0  = 1.0f / scale[oi0];
    const float trs0 = trans[oi0] * rs0;
    const float rs1  = 1.0f / scale[oi1];
    const float trs1 = trans[oi1] * rs1;
    const float* wpa = wconv + oi0 * 9;
    const float a00 = wpa[0], a01 = wpa[1], a02 = wpa[2];
    const float a10 = wpa[3], a11 = wpa[4], a12 = wpa[5];
    const float a20 = wpa[6], a21 = wpa[7], a22 = wpa[8];
    const float* wpb = wconv + oi1 * 9;
    const float b00 = wpb[0], b01 = wpb[1], b02 = wpb[2];
    const float b10 = wpb[3], b11 = wpb[4], b12 = wpb[5];
    const float b20 = wpb[6], b21 = wpb[7], b22 = wpb[8];
    const float* xi0 = xb + (size_t)i0 * 128 * 128;
    const float* xi1 = xi0 + 128 * 128;

#pragma unroll
    for (int j = 0; j < RSTRIP + 2; ++j) {
      const int ir = r0 + j - 1;           // input row (wave-uniform)
      if (ir >= 0 && ir < 128) {           // outside rows: wt = 0 (zero pad)
        const float2 xva = *(const float2*)(xi0 + ir * 128 + c0);
        const float2 xvb = *(const float2*)(xi1 + ir * 128 + c0);
        // psi((x - t)/s) = MH_C * (u - 1) * exp(-u/2), u = sx^2
        const float sa0 = fmaf(xva.x, rs0, -trs0);
        const float sa1 = fmaf(xva.y, rs0, -trs0);
        const float sb0 = fmaf(xvb.x, rs1, -trs1);
        const float sb1 = fmaf(xvb.y, rs1, -trs1);
        const float ua0 = sa0 * sa0, ua1 = sa1 * sa1;
        const float ub0 = sb0 * sb0, ub1 = sb1 * sb1;
        const float ea0 = __builtin_amdgcn_exp2f(ua0 * NHL2E);
        const float ea1 = __builtin_amdgcn_exp2f(ua1 * NHL2E);
        const float eb0 = __builtin_amdgcn_exp2f(ub0 * NHL2E);
        const float eb1 = __builtin_amdgcn_exp2f(ub1 * NHL2E);
        const float pa0 = fmaf(mhc, ua0, -mhc) * ea0;
        const float pa1 = fmaf(mhc, ua1, -mhc) * ea1;
        const float pb0 = fmaf(mhc, ub0, -mhc) * eb0;
        const float pb1 = fmaf(mhc, ub1, -mhc) * eb1;
        // horizontal halo from neighbor lanes; image edges zero-pad
        float pla = __shfl_up(pa1, 1);
        float pra = __shfl_down(pa0, 1);
        float plb = __shfl_up(pb1, 1);
        float prb = __shfl_down(pb0, 1);
        if (lane == 0)  { pla = 0.f; plb = 0.f; }
        if (lane == 63) { pra = 0.f; prb = 0.f; }

#define TAPS(W0, W1, W2, PL, P0, P1, PR, R)          \
        acc[R][0] = fmaf(W0, PL, acc[R][0]);         \
        acc[R][0] = fmaf(W1, P0, acc[R][0]);         \
        acc[R][0] = fmaf(W2, P1, acc[R][0]);         \
        acc[R][1] = fmaf(W0, P0, acc[R][1]);         \
        acc[R][1] = fmaf(W1, P1, acc[R][1]);         \
        acc[R][1] = fmaf(W2, PR, acc[R][1]);

        // input row ir feeds output rows ir+1 (kh=0), ir (kh=1), ir-1 (kh=2)
        if (j <= RSTRIP - 1) {
          TAPS(a00, a01, a02, pla, pa0, pa1, pra, j)
          TAPS(b00, b01, b02, plb, pb0, pb1, prb, j)
        }
        if (j >= 1 && j <= RSTRIP) {
          TAPS(a10, a11, a12, pla, pa0, pa1, pra, j - 1)
          TAPS(b10, b11, b12, plb, pb0, pb1, prb, j - 1)
        }
        if (j >= 2) {
          TAPS(a20, a21, a22, pla, pa0, pa1, pra, j - 2)
          TAPS(b20, b21, b22, plb, pb0, pb1, prb, j - 2)
        }
#undef TAPS
      }
    }
  }

  // reduce the four i-quarters through LDS (lane-major: conflict-free)
  __shared__ float red[3][RSTRIP * 2][64];   // 12 KB
  if (iq != 0) {
#pragma unroll
    for (int r = 0; r < RSTRIP; ++r) {
      red[iq - 1][r * 2 + 0][lane] = acc[r][0];
      red[iq - 1][r * 2 + 1][lane] = acc[r][1];
    }
  }
  __syncthreads();
  if (iq == 0) {
    float* yb = y + (((size_t)b * 32 + o) * 128 + r0) * 128 + c0;
#pragma unroll
    for (int r = 0; r < RSTRIP; ++r) {
      const float v0 = acc[r][0] + red[0][r * 2 + 0][lane]
                     + red[1][r * 2 + 0][lane] + red[2][r * 2 + 0][lane];
      const float v1 = acc[r][1] + red[0][r * 2 + 1][lane]
                     + red[1][r * 2 + 1][lane] + red[2][r * 2 + 1][lane];
      *(float2*)(yb + (size_t)r * 128) = make_float2(v0, v1);
    }
  }
}

__global__ __launch_bounds__(256) void mix1x1(
    const float* __restrict__ y,    // (B, O, H*W)
    const float* __restrict__ fw,   // (O_out, O_in)
    float* __restrict__ out)        // (B, O, H*W)
{
  const int px = blockIdx.x * 256 + threadIdx.x;  // 0..16383
  const int b  = blockIdx.y;
  const float* yb = y + (size_t)b * 32 * 16384 + px;
  float v[32];
#pragma unroll
  for (int o = 0; o < 32; ++o) v[o] = yb[(size_t)o * 16384];
  float* ob = out + (size_t)b * 32 * 16384 + px;
#pragma unroll
  for (int p = 0; p < 32; ++p) {
    float a = 0.f;
#pragma unroll
    for (int o = 0; o < 32; ++o) a = fmaf(fw[p * 32 + o], v[o], a);
    ob[(size_t)p * 16384] = a;
  }
}

extern "C" void kernel_launch(void* const* d_in, const int* in_sizes, int n_in,
                              void* d_out, int out_size, void* d_ws, size_t ws_size,
                              hipStream_t stream) {
  const float* x     = (const float*)d_in[0];
  const float* scale = (const float*)d_in[1];
  const float* trans = (const float*)d_in[2];
  const float* wconv = (const float*)d_in[3];
  const float* fw    = (const float*)d_in[4];
  float* out = (float*)d_out;
  float* y   = (float*)d_ws;   // 4*32*128*128 floats = 8.39 MB

  const float mhc = (float)(2.0 / (sqrt(3.0) * pow(M_PI, 0.25)));

  dim3 g1(128 / RSTRIP, 32, 4);  // (strips, o, b) = 2048 blocks x 256 thr
  wavelet_grouped_conv<<<g1, 256, 0, stream>>>(x, scale, trans, wconv, y, mhc);

  dim3 g2(16384 / 256, 4);       // (pixel tiles, b)
  mix1x1<<<g2, 256, 0, stream>>>(y, fw, out);
}

// Round 4
// 344.124 us; speedup vs baseline: 1.6046x; 1.6046x over previous
//
#include <hip/hip_runtime.h>
#include <math.h>

// WaveletLayerND: fused mexican-hat wavelet + grouped 3x3 conv (kernel 1),
// then 1x1 channel mix (kernel 2). B=4, O=I=32, H=W=128, fp32 throughout.
//
// Kernel 1 layout: 256-thread blocks = 4 waves = one o-channel, i split 4-way
// (8 input channels per wave). 16 strips x 32 o x 4 b = 2048 blocks.
// __launch_bounds__(256,4): 128-VGPR cap -> natural ~80-VGPR footprint fits,
// NO spill (round 3 lesson: (256,6)'s 85-cap spilled acc to scratch, 3.3 GB
// of HBM write traffic). 4 blocks/CU = 16 waves/CU = 50% occupancy.
// 3 waves write partials to LDS; wave 0 reduces and stores y.

#define RSTRIP 8   // output rows per wave

__global__ __launch_bounds__(256, 4) void wavelet_grouped_conv(
    const float* __restrict__ x,      // (B, I, H, W)
    const float* __restrict__ scale,  // (O*I)
    const float* __restrict__ trans,  // (O*I)
    const float* __restrict__ wconv,  // (O, I, 3, 3)
    float* __restrict__ y,            // (B, O, H, W) workspace
    float mhc)
{
  const int tid   = threadIdx.x;
  const int lane  = tid & 63;
  const int iq    = tid >> 6;          // 0..3: which i-quarter this wave owns
  const int strip = blockIdx.x;        // 0..15
  const int o     = blockIdx.y;        // 0..31
  const int b     = blockIdx.z;        // 0..3
  const int r0    = strip * RSTRIP;
  const int c0    = lane << 1;         // this thread's two columns

  const float NHL2E = -0.72134752044448170f; // -0.5 * log2(e)

  float acc[RSTRIP][2];
#pragma unroll
  for (int r = 0; r < RSTRIP; ++r) { acc[r][0] = 0.f; acc[r][1] = 0.f; }

  const float* xb = x + (size_t)b * 32 * 128 * 128;

  for (int ii = 0; ii < 8; ii += 2) {
    const int i0 = iq * 8 + ii;                 // wave-uniform
    const int oi0 = __builtin_amdgcn_readfirstlane(o * 32 + i0);
    const int oi1 = oi0 + 1;
    const float rs0  = 1.0f / scale[oi0];
    const float trs0 = trans[oi0] * rs0;
    const float rs1  = 1.0f / scale[oi1];
    const float trs1 = trans[oi1] * rs1;
    const float* wpa = wconv + oi0 * 9;
    const float a00 = wpa[0], a01 = wpa[1], a02 = wpa[2];
    const float a10 = wpa[3], a11 = wpa[4], a12 = wpa[5];
    const float a20 = wpa[6], a21 = wpa[7], a22 = wpa[8];
    const float* wpb = wconv + oi1 * 9;
    const float b00 = wpb[0], b01 = wpb[1], b02 = wpb[2];
    const float b10 = wpb[3], b11 = wpb[4], b12 = wpb[5];
    const float b20 = wpb[6], b21 = wpb[7], b22 = wpb[8];
    const float* xi0 = xb + (size_t)i0 * 128 * 128;
    const float* xi1 = xi0 + 128 * 128;

#pragma unroll
    for (int j = 0; j < RSTRIP + 2; ++j) {
      const int ir = r0 + j - 1;           // input row (wave-uniform)
      if (ir >= 0 && ir < 128) {           // outside rows: wt = 0 (zero pad)
        const float2 xva = *(const float2*)(xi0 + ir * 128 + c0);
        const float2 xvb = *(const float2*)(xi1 + ir * 128 + c0);
        // psi((x - t)/s) = MH_C * (u - 1) * exp(-u/2), u = sx^2
        const float sa0 = fmaf(xva.x, rs0, -trs0);
        const float sa1 = fmaf(xva.y, rs0, -trs0);
        const float sb0 = fmaf(xvb.x, rs1, -trs1);
        const float sb1 = fmaf(xvb.y, rs1, -trs1);
        const float ua0 = sa0 * sa0, ua1 = sa1 * sa1;
        const float ub0 = sb0 * sb0, ub1 = sb1 * sb1;
        const float ea0 = __builtin_amdgcn_exp2f(ua0 * NHL2E);
        const float ea1 = __builtin_amdgcn_exp2f(ua1 * NHL2E);
        const float eb0 = __builtin_amdgcn_exp2f(ub0 * NHL2E);
        const float eb1 = __builtin_amdgcn_exp2f(ub1 * NHL2E);
        const float pa0 = fmaf(mhc, ua0, -mhc) * ea0;
        const float pa1 = fmaf(mhc, ua1, -mhc) * ea1;
        const float pb0 = fmaf(mhc, ub0, -mhc) * eb0;
        const float pb1 = fmaf(mhc, ub1, -mhc) * eb1;
        // horizontal halo from neighbor lanes; image edges zero-pad
        float pla = __shfl_up(pa1, 1);
        float pra = __shfl_down(pa0, 1);
        float plb = __shfl_up(pb1, 1);
        float prb = __shfl_down(pb0, 1);
        if (lane == 0)  { pla = 0.f; plb = 0.f; }
        if (lane == 63) { pra = 0.f; prb = 0.f; }

#define TAPS(W0, W1, W2, PL, P0, P1, PR, R)          \
        acc[R][0] = fmaf(W0, PL, acc[R][0]);         \
        acc[R][0] = fmaf(W1, P0, acc[R][0]);         \
        acc[R][0] = fmaf(W2, P1, acc[R][0]);         \
        acc[R][1] = fmaf(W0, P0, acc[R][1]);         \
        acc[R][1] = fmaf(W1, P1, acc[R][1]);         \
        acc[R][1] = fmaf(W2, PR, acc[R][1]);

        // input row ir feeds output rows ir+1 (kh=0), ir (kh=1), ir-1 (kh=2)
        if (j <= RSTRIP - 1) {
          TAPS(a00, a01, a02, pla, pa0, pa1, pra, j)
          TAPS(b00, b01, b02, plb, pb0, pb1, prb, j)
        }
        if (j >= 1 && j <= RSTRIP) {
          TAPS(a10, a11, a12, pla, pa0, pa1, pra, j - 1)
          TAPS(b10, b11, b12, plb, pb0, pb1, prb, j - 1)
        }
        if (j >= 2) {
          TAPS(a20, a21, a22, pla, pa0, pa1, pra, j - 2)
          TAPS(b20, b21, b22, plb, pb0, pb1, prb, j - 2)
        }
#undef TAPS
      }
    }
  }

  // reduce the four i-quarters through LDS (lane-major: conflict-free)
  __shared__ float red[3][RSTRIP * 2][64];   // 12 KB
  if (iq != 0) {
#pragma unroll
    for (int r = 0; r < RSTRIP; ++r) {
      red[iq - 1][r * 2 + 0][lane] = acc[r][0];
      red[iq - 1][r * 2 + 1][lane] = acc[r][1];
    }
  }
  __syncthreads();
  if (iq == 0) {
    float* yb = y + (((size_t)b * 32 + o) * 128 + r0) * 128 + c0;
#pragma unroll
    for (int r = 0; r < RSTRIP; ++r) {
      const float v0 = acc[r][0] + red[0][r * 2 + 0][lane]
                     + red[1][r * 2 + 0][lane] + red[2][r * 2 + 0][lane];
      const float v1 = acc[r][1] + red[0][r * 2 + 1][lane]
                     + red[1][r * 2 + 1][lane] + red[2][r * 2 + 1][lane];
      *(float2*)(yb + (size_t)r * 128) = make_float2(v0, v1);
    }
  }
}

__global__ __launch_bounds__(256) void mix1x1(
    const float* __restrict__ y,    // (B, O, H*W)
    const float* __restrict__ fw,   // (O_out, O_in)
    float* __restrict__ out)        // (B, O, H*W)
{
  const int px = blockIdx.x * 256 + threadIdx.x;  // 0..16383
  const int b  = blockIdx.y;
  const float* yb = y + (size_t)b * 32 * 16384 + px;
  float v[32];
#pragma unroll
  for (int o = 0; o < 32; ++o) v[o] = yb[(size_t)o * 16384];
  float* ob = out + (size_t)b * 32 * 16384 + px;
#pragma unroll
  for (int p = 0; p < 32; ++p) {
    float a = 0.f;
#pragma unroll
    for (int o = 0; o < 32; ++o) a = fmaf(fw[p * 32 + o], v[o], a);
    ob[(size_t)p * 16384] = a;
  }
}

extern "C" void kernel_launch(void* const* d_in, const int* in_sizes, int n_in,
                              void* d_out, int out_size, void* d_ws, size_t ws_size,
                              hipStream_t stream) {
  const float* x     = (const float*)d_in[0];
  const float* scale = (const float*)d_in[1];
  const float* trans = (const float*)d_in[2];
  const float* wconv = (const float*)d_in[3];
  const float* fw    = (const float*)d_in[4];
  float* out = (float*)d_out;
  float* y   = (float*)d_ws;   // 4*32*128*128 floats = 8.39 MB

  const float mhc = (float)(2.0 / (sqrt(3.0) * pow(M_PI, 0.25)));

  dim3 g1(128 / RSTRIP, 32, 4);  // (strips, o, b) = 2048 blocks x 256 thr
  wavelet_grouped_conv<<<g1, 256, 0, stream>>>(x, scale, trans, wconv, y, mhc);

  dim3 g2(16384 / 256, 4);       // (pixel tiles, b)
  mix1x1<<<g2, 256, 0, stream>>>(y, fw, out);
}

// Round 5
// 82.625 us; speedup vs baseline: 6.6829x; 4.1649x over previous
//
#include <hip/hip_runtime.h>
#include <math.h>

// WaveletLayerND: fused mexican-hat wavelet + grouped 3x3 conv (kernel 1),
// then 1x1 channel mix (kernel 2). B=4, O=I=32, H=W=128, fp32 throughout.
//
// Kernel 1 layout: 256-thread blocks = 4 waves = one o-channel, i split 4-way
// (8 input channels per wave). 16 strips x 32 o x 4 b = 2048 blocks.
// NO min-waves launch_bounds arg: on this hipcc the cap is ~256/arg VGPRs
// ((256,6)->40, (256,4)->64 — both spilled the ~76-VGPR natural footprint to
// scratch: 0.5-3 GB HBM write traffic, rounds 3-4). Natural 72-76 VGPRs
// -> 6 waves/SIMD allowed by HW; the 8192-wave grid supplies 32 waves/CU.
// 3 waves write partials to LDS; wave 0 reduces and stores y.

#define RSTRIP 8   // output rows per wave

__global__ __launch_bounds__(256) void wavelet_grouped_conv(
    const float* __restrict__ x,      // (B, I, H, W)
    const float* __restrict__ scale,  // (O*I)
    const float* __restrict__ trans,  // (O*I)
    const float* __restrict__ wconv,  // (O, I, 3, 3)
    float* __restrict__ y,            // (B, O, H, W) workspace
    float mhc)
{
  const int tid   = threadIdx.x;
  const int lane  = tid & 63;
  const int iq    = tid >> 6;          // 0..3: which i-quarter this wave owns
  const int strip = blockIdx.x;        // 0..15
  const int o     = blockIdx.y;        // 0..31
  const int b     = blockIdx.z;        // 0..3
  const int r0    = strip * RSTRIP;
  const int c0    = lane << 1;         // this thread's two columns

  const float NHL2E = -0.72134752044448170f; // -0.5 * log2(e)

  float acc[RSTRIP][2];
#pragma unroll
  for (int r = 0; r < RSTRIP; ++r) { acc[r][0] = 0.f; acc[r][1] = 0.f; }

  const float* xb = x + (size_t)b * 32 * 128 * 128;

  for (int ii = 0; ii < 8; ii += 2) {
    const int i0 = iq * 8 + ii;                 // wave-uniform
    const int oi0 = __builtin_amdgcn_readfirstlane(o * 32 + i0);
    const int oi1 = oi0 + 1;
    const float rs0  = 1.0f / scale[oi0];
    const float trs0 = trans[oi0] * rs0;
    const float rs1  = 1.0f / scale[oi1];
    const float trs1 = trans[oi1] * rs1;
    const float* wpa = wconv + oi0 * 9;
    const float a00 = wpa[0], a01 = wpa[1], a02 = wpa[2];
    const float a10 = wpa[3], a11 = wpa[4], a12 = wpa[5];
    const float a20 = wpa[6], a21 = wpa[7], a22 = wpa[8];
    const float* wpb = wconv + oi1 * 9;
    const float b00 = wpb[0], b01 = wpb[1], b02 = wpb[2];
    const float b10 = wpb[3], b11 = wpb[4], b12 = wpb[5];
    const float b20 = wpb[6], b21 = wpb[7], b22 = wpb[8];
    const float* xi0 = xb + (size_t)i0 * 128 * 128;
    const float* xi1 = xi0 + 128 * 128;

#pragma unroll
    for (int j = 0; j < RSTRIP + 2; ++j) {
      const int ir = r0 + j - 1;           // input row (wave-uniform)
      if (ir >= 0 && ir < 128) {           // outside rows: wt = 0 (zero pad)
        const float2 xva = *(const float2*)(xi0 + ir * 128 + c0);
        const float2 xvb = *(const float2*)(xi1 + ir * 128 + c0);
        // psi((x - t)/s) = MH_C * (u - 1) * exp(-u/2), u = sx^2
        const float sa0 = fmaf(xva.x, rs0, -trs0);
        const float sa1 = fmaf(xva.y, rs0, -trs0);
        const float sb0 = fmaf(xvb.x, rs1, -trs1);
        const float sb1 = fmaf(xvb.y, rs1, -trs1);
        const float ua0 = sa0 * sa0, ua1 = sa1 * sa1;
        const float ub0 = sb0 * sb0, ub1 = sb1 * sb1;
        const float ea0 = __builtin_amdgcn_exp2f(ua0 * NHL2E);
        const float ea1 = __builtin_amdgcn_exp2f(ua1 * NHL2E);
        const float eb0 = __builtin_amdgcn_exp2f(ub0 * NHL2E);
        const float eb1 = __builtin_amdgcn_exp2f(ub1 * NHL2E);
        const float pa0 = fmaf(mhc, ua0, -mhc) * ea0;
        const float pa1 = fmaf(mhc, ua1, -mhc) * ea1;
        const float pb0 = fmaf(mhc, ub0, -mhc) * eb0;
        const float pb1 = fmaf(mhc, ub1, -mhc) * eb1;
        // horizontal halo from neighbor lanes; image edges zero-pad
        float pla = __shfl_up(pa1, 1);
        float pra = __shfl_down(pa0, 1);
        float plb = __shfl_up(pb1, 1);
        float prb = __shfl_down(pb0, 1);
        if (lane == 0)  { pla = 0.f; plb = 0.f; }
        if (lane == 63) { pra = 0.f; prb = 0.f; }

#define TAPS(W0, W1, W2, PL, P0, P1, PR, R)          \
        acc[R][0] = fmaf(W0, PL, acc[R][0]);         \
        acc[R][0] = fmaf(W1, P0, acc[R][0]);         \
        acc[R][0] = fmaf(W2, P1, acc[R][0]);         \
        acc[R][1] = fmaf(W0, P0, acc[R][1]);         \
        acc[R][1] = fmaf(W1, P1, acc[R][1]);         \
        acc[R][1] = fmaf(W2, PR, acc[R][1]);

        // input row ir feeds output rows ir+1 (kh=0), ir (kh=1), ir-1 (kh=2)
        if (j <= RSTRIP - 1) {
          TAPS(a00, a01, a02, pla, pa0, pa1, pra, j)
          TAPS(b00, b01, b02, plb, pb0, pb1, prb, j)
        }
        if (j >= 1 && j <= RSTRIP) {
          TAPS(a10, a11, a12, pla, pa0, pa1, pra, j - 1)
          TAPS(b10, b11, b12, plb, pb0, pb1, prb, j - 1)
        }
        if (j >= 2) {
          TAPS(a20, a21, a22, pla, pa0, pa1, pra, j - 2)
          TAPS(b20, b21, b22, plb, pb0, pb1, prb, j - 2)
        }
#undef TAPS
      }
    }
  }

  // reduce the four i-quarters through LDS (lane-major: conflict-free)
  __shared__ float red[3][RSTRIP * 2][64];   // 12 KB
  if (iq != 0) {
#pragma unroll
    for (int r = 0; r < RSTRIP; ++r) {
      red[iq - 1][r * 2 + 0][lane] = acc[r][0];
      red[iq - 1][r * 2 + 1][lane] = acc[r][1];
    }
  }
  __syncthreads();
  if (iq == 0) {
    float* yb = y + (((size_t)b * 32 + o) * 128 + r0) * 128 + c0;
#pragma unroll
    for (int r = 0; r < RSTRIP; ++r) {
      const float v0 = acc[r][0] + red[0][r * 2 + 0][lane]
                     + red[1][r * 2 + 0][lane] + red[2][r * 2 + 0][lane];
      const float v1 = acc[r][1] + red[0][r * 2 + 1][lane]
                     + red[1][r * 2 + 1][lane] + red[2][r * 2 + 1][lane];
      *(float2*)(yb + (size_t)r * 128) = make_float2(v0, v1);
    }
  }
}

__global__ __launch_bounds__(256) void mix1x1(
    const float* __restrict__ y,    // (B, O, H*W)
    const float* __restrict__ fw,   // (O_out, O_in)
    float* __restrict__ out)        // (B, O, H*W)
{
  const int px = blockIdx.x * 256 + threadIdx.x;  // 0..16383
  const int b  = blockIdx.y;
  const float* yb = y + (size_t)b * 32 * 16384 + px;
  float v[32];
#pragma unroll
  for (int o = 0; o < 32; ++o) v[o] = yb[(size_t)o * 16384];
  float* ob = out + (size_t)b * 32 * 16384 + px;
#pragma unroll
  for (int p = 0; p < 32; ++p) {
    float a = 0.f;
#pragma unroll
    for (int o = 0; o < 32; ++o) a = fmaf(fw[p * 32 + o], v[o], a);
    ob[(size_t)p * 16384] = a;
  }
}

extern "C" void kernel_launch(void* const* d_in, const int* in_sizes, int n_in,
                              void* d_out, int out_size, void* d_ws, size_t ws_size,
                              hipStream_t stream) {
  const float* x     = (const float*)d_in[0];
  const float* scale = (const float*)d_in[1];
  const float* trans = (const float*)d_in[2];
  const float* wconv = (const float*)d_in[3];
  const float* fw    = (const float*)d_in[4];
  float* out = (float*)d_out;
  float* y   = (float*)d_ws;   // 4*32*128*128 floats = 8.39 MB

  const float mhc = (float)(2.0 / (sqrt(3.0) * pow(M_PI, 0.25)));

  dim3 g1(128 / RSTRIP, 32, 4);  // (strips, o, b) = 2048 blocks x 256 thr
  wavelet_grouped_conv<<<g1, 256, 0, stream>>>(x, scale, trans, wconv, y, mhc);

  dim3 g2(16384 / 256, 4);       // (pixel tiles, b)
  mix1x1<<<g2, 256, 0, stream>>>(y, fw, out);
}

// Round 6
// 79.228 us; speedup vs baseline: 6.9695x; 1.0429x over previous
//
#include <hip/hip_runtime.h>
#include <math.h>

// WaveletLayerND: fused mexican-hat wavelet + grouped 3x3 conv (kernel 1),
// then 1x1 channel mix (kernel 2). B=4, O=I=32, H=W=128, fp32 throughout.
//
// Round 6: packed-FP32 rewrite of the hot loop. Each thread owns a column
// pair, so conv taps become v_pk_fma_f32 (VOP3P, 2 FMA/issue):
//   acc += w0*{pl,p0} + w1*{p0,p1} + w2*{p1,pr}   (3 pk_fma per row-region)
// psi is packed the same way. Halo via raw ds_bpermute with hoisted lane
// addresses. NO launch_bounds min-waves arg (rounds 3-4: cap ~256/arg VGPRs
// spilled the ~76-VGPR footprint -> GBs of scratch traffic).

#define RSTRIP 8   // output rows per wave

typedef float v2f __attribute__((ext_vector_type(2)));

static __device__ __forceinline__ v2f vfma(float w, v2f a, v2f c) {
  return __builtin_elementwise_fma(a, (v2f){w, w}, c);
}
static __device__ __forceinline__ float bperm(int addr, float v) {
  return __int_as_float(__builtin_amdgcn_ds_bpermute(addr, __float_as_int(v)));
}

__global__ __launch_bounds__(256) void wavelet_grouped_conv(
    const float* __restrict__ x,      // (B, I, H, W)
    const float* __restrict__ scale,  // (O*I)
    const float* __restrict__ trans,  // (O*I)
    const float* __restrict__ wconv,  // (O, I, 3, 3)
    float* __restrict__ y,            // (B, O, H, W) workspace
    float mhc)
{
  const int tid   = threadIdx.x;
  const int lane  = tid & 63;
  const int iq    = tid >> 6;          // 0..3: which i-quarter this wave owns
  const int strip = blockIdx.x;        // 0..15
  const int o     = blockIdx.y;        // 0..31
  const int b     = blockIdx.z;        // 0..3
  const int r0    = strip * RSTRIP;
  const int c0    = lane << 1;         // this thread's two columns

  // hoisted bpermute byte-addresses: lane-1 and lane+1 (mod 64)
  const int a_up = ((lane + 63) & 63) << 2;
  const int a_dn = ((lane +  1) & 63) << 2;

  const float NHL2E = -0.72134752044448170f; // -0.5 * log2(e)

  v2f acc[RSTRIP];
#pragma unroll
  for (int r = 0; r < RSTRIP; ++r) acc[r] = (v2f){0.f, 0.f};

  const float* xb = x + (size_t)b * 32 * 128 * 128;

  for (int ii = 0; ii < 8; ii += 2) {
    const int i0 = iq * 8 + ii;                 // wave-uniform
    const int oi0 = __builtin_amdgcn_readfirstlane(o * 32 + i0);
    const int oi1 = oi0 + 1;
    const float rs0  = 1.0f / scale[oi0];
    const float trs0 = trans[oi0] * rs0;
    const float rs1  = 1.0f / scale[oi1];
    const float trs1 = trans[oi1] * rs1;
    const float* wpa = wconv + oi0 * 9;
    const float a00 = wpa[0], a01 = wpa[1], a02 = wpa[2];
    const float a10 = wpa[3], a11 = wpa[4], a12 = wpa[5];
    const float a20 = wpa[6], a21 = wpa[7], a22 = wpa[8];
    const float* wpb = wconv + oi1 * 9;
    const float b00 = wpb[0], b01 = wpb[1], b02 = wpb[2];
    const float b10 = wpb[3], b11 = wpb[4], b12 = wpb[5];
    const float b20 = wpb[6], b21 = wpb[7], b22 = wpb[8];
    const float* xi0 = xb + (size_t)i0 * 128 * 128;
    const float* xi1 = xi0 + 128 * 128;

#pragma unroll
    for (int j = 0; j < RSTRIP + 2; ++j) {
      const int ir = r0 + j - 1;           // input row (wave-uniform)
      if (ir >= 0 && ir < 128) {           // outside rows: wt = 0 (zero pad)
        const v2f xva = *(const v2f*)(xi0 + ir * 128 + c0);
        const v2f xvb = *(const v2f*)(xi1 + ir * 128 + c0);
        // psi((x-t)/s) = MH_C*(u-1)*exp(-u/2), u = sx^2  — packed
        const v2f sxa = __builtin_elementwise_fma(xva, (v2f){rs0, rs0},
                                                  (v2f){-trs0, -trs0});
        const v2f sxb = __builtin_elementwise_fma(xvb, (v2f){rs1, rs1},
                                                  (v2f){-trs1, -trs1});
        const v2f ua = sxa * sxa;
        const v2f ub = sxb * sxb;
        v2f ea, eb;
        ea.x = __builtin_amdgcn_exp2f(ua.x * NHL2E);
        ea.y = __builtin_amdgcn_exp2f(ua.y * NHL2E);
        eb.x = __builtin_amdgcn_exp2f(ub.x * NHL2E);
        eb.y = __builtin_amdgcn_exp2f(ub.y * NHL2E);
        const v2f pa = __builtin_elementwise_fma(ua, (v2f){mhc, mhc},
                                                 (v2f){-mhc, -mhc}) * ea;
        const v2f pb = __builtin_elementwise_fma(ub, (v2f){mhc, mhc},
                                                 (v2f){-mhc, -mhc}) * eb;
        // halo: pl = psi(c0-1) from lane-1, pr = psi(c0+2) from lane+1
        float pla = bperm(a_up, pa.y);
        float pra = bperm(a_dn, pa.x);
        float plb = bperm(a_up, pb.y);
        float prb = bperm(a_dn, pb.x);
        if (lane == 0)  { pla = 0.f; plb = 0.f; }
        if (lane == 63) { pra = 0.f; prb = 0.f; }
        const v2f La = (v2f){pla, pa.x};   // {psi(c0-1), psi(c0)}
        const v2f Ra = (v2f){pa.y, pra};   // {psi(c0+1), psi(c0+2)}
        const v2f Lb = (v2f){plb, pb.x};
        const v2f Rb = (v2f){pb.y, prb};

        // acc.x += w0*pl + w1*p0 + w2*p1 ; acc.y += w0*p0 + w1*p1 + w2*pr
#define TAPS(W0, W1, W2, L, T, R, RR)                      \
        acc[RR] = vfma(W0, L, acc[RR]);                    \
        acc[RR] = vfma(W1, T, acc[RR]);                    \
        acc[RR] = vfma(W2, R, acc[RR]);

        // input row ir feeds output rows ir+1 (kh=0), ir (kh=1), ir-1 (kh=2)
        if (j <= RSTRIP - 1) {
          TAPS(a00, a01, a02, La, pa, Ra, j)
          TAPS(b00, b01, b02, Lb, pb, Rb, j)
        }
        if (j >= 1 && j <= RSTRIP) {
          TAPS(a10, a11, a12, La, pa, Ra, j - 1)
          TAPS(b10, b11, b12, Lb, pb, Rb, j - 1)
        }
        if (j >= 2) {
          TAPS(a20, a21, a22, La, pa, Ra, j - 2)
          TAPS(b20, b21, b22, Lb, pb, Rb, j - 2)
        }
#undef TAPS
      }
    }
  }

  // reduce the four i-quarters through LDS (lane-major; b64 2-way is free)
  __shared__ v2f red[3][RSTRIP][64];   // 12 KB
  if (iq != 0) {
#pragma unroll
    for (int r = 0; r < RSTRIP; ++r) red[iq - 1][r][lane] = acc[r];
  }
  __syncthreads();
  if (iq == 0) {
    float* yb = y + (((size_t)b * 32 + o) * 128 + r0) * 128 + c0;
#pragma unroll
    for (int r = 0; r < RSTRIP; ++r) {
      const v2f v = acc[r] + red[0][r][lane] + red[1][r][lane] + red[2][r][lane];
      *(v2f*)(yb + (size_t)r * 128) = v;
    }
  }
}

__global__ __launch_bounds__(256) void mix1x1(
    const float* __restrict__ y,    // (B, O, H*W)
    const float* __restrict__ fw,   // (O_out, O_in)
    float* __restrict__ out)        // (B, O, H*W)
{
  const int px = blockIdx.x * 256 + threadIdx.x;  // 0..16383
  const int b  = blockIdx.y;
  const float* yb = y + (size_t)b * 32 * 16384 + px;
  float v[32];
#pragma unroll
  for (int o = 0; o < 32; ++o) v[o] = yb[(size_t)o * 16384];
  float* ob = out + (size_t)b * 32 * 16384 + px;
#pragma unroll
  for (int p = 0; p < 32; ++p) {
    float a = 0.f;
#pragma unroll
    for (int o = 0; o < 32; ++o) a = fmaf(fw[p * 32 + o], v[o], a);
    ob[(size_t)p * 16384] = a;
  }
}

extern "C" void kernel_launch(void* const* d_in, const int* in_sizes, int n_in,
                              void* d_out, int out_size, void* d_ws, size_t ws_size,
                              hipStream_t stream) {
  const float* x     = (const float*)d_in[0];
  const float* scale = (const float*)d_in[1];
  const float* trans = (const float*)d_in[2];
  const float* wconv = (const float*)d_in[3];
  const float* fw    = (const float*)d_in[4];
  float* out = (float*)d_out;
  float* y   = (float*)d_ws;   // 4*32*128*128 floats = 8.39 MB

  const float mhc = (float)(2.0 / (sqrt(3.0) * pow(M_PI, 0.25)));

  dim3 g1(128 / RSTRIP, 32, 4);  // (strips, o, b) = 2048 blocks x 256 thr
  wavelet_grouped_conv<<<g1, 256, 0, stream>>>(x, scale, trans, wconv, y, mhc);

  dim3 g2(16384 / 256, 4);       // (pixel tiles, b)
  mix1x1<<<g2, 256, 0, stream>>>(y, fw, out);
}